// Round 2
// 154.288 us; speedup vs baseline: 1.1342x; 1.1342x over previous
//
#include <hip/hip_runtime.h>

// ComplexMixture: B=32, S=8192, D=64, fp32 in/out.
// out_real = (R^T R + I^T I)/S   [B,64,64]
// out_imag = (R^T I - (R^T I)^T)/S
// bf16 MFMA Gram, split-K partials in d_ws + reduce kernel.
// R4 (= R3 resubmit + fixes): float4 staging (16 loads/thread/tile vs 64
//     scalar), BOTH-sides conflict-free LDS permutation
//     p(d) = d ^ ((d>>3)&1) ^ (((d>>4)&1)<<1),
//     double-buffered LDS + raw s_barrier (vmcnt never drained at barrier),
//     sched_barrier(0) fences on both sides of each barrier,
//     launch_bounds(256,2), CHUNKS 16.

#define BATCH 32
#define SEQ   8192
#define DD    64
#define BK    128

typedef __bf16 bf16x8 __attribute__((ext_vector_type(8)));
typedef float  f32x16 __attribute__((ext_vector_type(16)));
typedef float  f32x4  __attribute__((ext_vector_type(4)));

__device__ __forceinline__ unsigned bf16pk(float a, float b) {
  unsigned ua = __builtin_bit_cast(unsigned, a);
  unsigned ub = __builtin_bit_cast(unsigned, b);
  ua = (ua + 0x7fffu + ((ua >> 16) & 1u)) >> 16;   // RNE to bf16
  ub = (ub + 0x7fffu + ((ub >> 16) & 1u)) >> 16;
  return (ua & 0xffffu) | (ub << 16);
}

// Column permutation for the LDS tile (uint4 units within a row):
//   p(d) = d ^ ((d>>3)&1) ^ (((d>>4)&1)<<1)
// Bijective on [0,64). Bank-quad = p mod 8.
//  - reads: lanes l=0..31 at d=c0+l -> every consecutive-8-lane group covers
//    all 8 bank-quads (p mod 8 bijective on each run {8a..8a+7}).
//  - writes: thread q in [0,16) writes d=4q+cc -> p(4q+cc) mod 8 bijective
//    over q mod 8 for each cc (high bits d3,d4 folded into low bits).
__device__ __forceinline__ int permd(int d) {
  return d ^ ((d >> 3) & 1) ^ (((d >> 4) & 1) << 1);
}

// LDS tile layout (per buffer): rows 0..15 = R, rows 16..31 = I.
// Row g holds s = tile_base + g*8 .. +8 (k-contiguous bf16x8 packs);
// column d sits at position permd(d) within the row.
template<int CHUNKS>
__global__ __launch_bounds__(256, 2) void gram_partial(
    const float* __restrict__ R, const float* __restrict__ I,
    float* __restrict__ ws)
{
  constexpr int SCHUNK = SEQ / CHUNKS;
  constexpr int NIT    = SCHUNK / BK;     // even (4 for CHUNKS=16, 8 for 8)
  __shared__ uint4 lds[2][32][64];        // 64 KB, 2 blocks/CU
  const int tid  = threadIdx.x;
  const int wave = tid >> 6;
  const int lane = tid & 63;
  const int b = blockIdx.x & 31;
  const int c = blockIdx.x >> 5;
  const float* Rb = R + (size_t)b * (SEQ * DD);
  const float* Ib = I + (size_t)b * (SEQ * DD);
  const int m0  = (wave >> 1) * 32;
  const int n0  = (wave & 1) * 32;
  const int l31 = lane & 31;
  const int lhi = lane >> 5;
  const int g   = tid >> 4;               // s-group 0..15
  const int q   = tid & 15;               // float4 column index
  const int pa  = permd(m0 + l31);
  const int pb  = permd(n0 + l31);
  int pw[4];
  #pragma unroll
  for (int cc = 0; cc < 4; ++cc) pw[cc] = permd(q * 4 + cc);

  f32x16 accR = {};   // rr + ii
  f32x16 accI = {};   // ri
  const int chunk0 = c * SCHUNK;

  f32x4 rv[8], iv[8];

  // Issue the full 32-load burst for tile `it_`; memory-clobber pins issue
  // order (loads may not sink past it -> stay in flight across MFMA phase).
#define LOADT(it_) do { \
    const size_t sb_ = (size_t)(chunk0 + (it_) * BK + g * 8); \
    const f32x4* pR_ = (const f32x4*)(Rb + sb_ * DD) + q; \
    const f32x4* pI_ = (const f32x4*)(Ib + sb_ * DD) + q; \
    _Pragma("unroll") \
    for (int j = 0; j < 8; ++j) { rv[j] = pR_[j * 16]; iv[j] = pI_[j * 16]; } \
    asm volatile("" ::: "memory"); \
  } while (0)

  // Convert + write tile into buffer buf_ (vmcnt waits happen here, after MFMA)
#define PACKW(buf_) do { \
    _Pragma("unroll") \
    for (int cc = 0; cc < 4; ++cc) { \
      uint4 qR_, qI_; \
      qR_.x = bf16pk(rv[0][cc], rv[1][cc]); qR_.y = bf16pk(rv[2][cc], rv[3][cc]); \
      qR_.z = bf16pk(rv[4][cc], rv[5][cc]); qR_.w = bf16pk(rv[6][cc], rv[7][cc]); \
      qI_.x = bf16pk(iv[0][cc], iv[1][cc]); qI_.y = bf16pk(iv[2][cc], iv[3][cc]); \
      qI_.z = bf16pk(iv[4][cc], iv[5][cc]); qI_.w = bf16pk(iv[6][cc], iv[7][cc]); \
      lds[buf_][g][pw[cc]]      = qR_; \
      lds[buf_][16 + g][pw[cc]] = qI_; \
    } \
  } while (0)

  // barrier with no vmcnt drain; sched_barrier both sides so no DS op or
  // MFMA can be moved across by the scheduler (guide rule #18).
#define TILEBAR() do { \
    __builtin_amdgcn_sched_barrier(0); \
    asm volatile("s_waitcnt lgkmcnt(0)" ::: "memory"); \
    __builtin_amdgcn_s_barrier(); \
    __builtin_amdgcn_sched_barrier(0); \
  } while (0)

  // prologue: stage tile 0
  LOADT(0);
  PACKW(0);
  TILEBAR();

  #pragma unroll
  for (int it = 0; it < NIT; ++it) {
    const int buf = it & 1;
    if (it + 1 < NIT) LOADT(it + 1);      // in flight across MFMA phase
    #pragma unroll
    for (int ks = 0; ks < BK / 16; ++ks) {
      const int kg = ks * 2 + lhi;
      bf16x8 aR = __builtin_bit_cast(bf16x8, lds[buf][kg][pa]);
      bf16x8 bR = __builtin_bit_cast(bf16x8, lds[buf][kg][pb]);
      bf16x8 aI = __builtin_bit_cast(bf16x8, lds[buf][16 + kg][pa]);
      bf16x8 bI = __builtin_bit_cast(bf16x8, lds[buf][16 + kg][pb]);
      accR = __builtin_amdgcn_mfma_f32_32x32x16_bf16(aR, bR, accR, 0, 0, 0);
      accR = __builtin_amdgcn_mfma_f32_32x32x16_bf16(aI, bI, accR, 0, 0, 0);
      accI = __builtin_amdgcn_mfma_f32_32x32x16_bf16(aR, bI, accI, 0, 0, 0);
    }
    if (it + 1 < NIT) {
      PACKW(buf ^ 1);                     // other buffer: no race with readers
      TILEBAR();                          // single barrier per tile
    }
  }
#undef LOADT
#undef PACKW
#undef TILEBAR

  // ---- epilogue: partials -> ws. slot 0 = rr+ii, slot 1 = ri - ri^T ----
  // Scratch lives in lds[0] (16.6 KB); last tile was read from lds[1]
  // (NIT even), so no barrier needed before scratch writes.
  float* wsR = ws + ((size_t)(c * 32 + b) * 2) * 4096;
  float* wsM = wsR + 4096;
  const int jj = n0 + l31;
  #pragma unroll
  for (int r = 0; r < 16; ++r) {
    const int i = m0 + (r & 3) + 8 * (r >> 2) + 4 * lhi;
    wsR[i * 64 + jj] = accR[r];
  }
  float* ldsf = (float*)lds;   // 64*65*4 = 16.6 KB scratch (inside lds[0])
  #pragma unroll
  for (int r = 0; r < 16; ++r) {
    const int i = m0 + (r & 3) + 8 * (r >> 2) + 4 * lhi;
    ldsf[i * 65 + jj] = accI[r];
  }
  __syncthreads();
  #pragma unroll
  for (int k = 0; k < 16; ++k) {
    const int e = tid + 256 * k;
    const int i = e >> 6, j = e & 63;
    wsM[e] = ldsf[i * 65 + j] - ldsf[j * 65 + i];
  }
}

// Sum CHUNKS chunk-partials, scale by 1/S. out = real[32][64][64] ++ imag[...].
template<int CHUNKS>
__global__ __launch_bounds__(256) void gram_reduce(
    const float4* __restrict__ ws, float4* __restrict__ out)
{
  const int o = blockIdx.x * 256 + threadIdx.x;   // 65536 float4s
  const int kind = o >> 15;
  const int rem  = o & 32767;
  const int b    = rem >> 10;
  const int e    = rem & 1023;
  const float inv = 1.0f / (float)SEQ;
  float sx = 0.f, sy = 0.f, sz = 0.f, sw = 0.f;
  #pragma unroll
  for (int cc = 0; cc < CHUNKS; ++cc) {
    float4 v = ws[((size_t)(cc * 32 + b) * 2 + kind) * 1024 + e];
    sx += v.x; sy += v.y; sz += v.z; sw += v.w;
  }
  float4 r; r.x = sx * inv; r.y = sy * inv; r.z = sz * inv; r.w = sw * inv;
  out[o] = r;
}

extern "C" void kernel_launch(void* const* d_in, const int* in_sizes, int n_in,
                              void* d_out, int out_size, void* d_ws, size_t ws_size,
                              hipStream_t stream) {
  const float* R = (const float*)d_in[0];
  const float* I = (const float*)d_in[1];
  float* out = (float*)d_out;
  float* ws  = (float*)d_ws;

  const size_t need16 = (size_t)16 * 32 * 2 * 4096 * 4;   // 16.8 MB
  if (ws_size >= need16) {
    gram_partial<16><<<BATCH * 16, 256, 0, stream>>>(R, I, ws);
    gram_reduce<16><<<256, 256, 0, stream>>>((const float4*)ws, (float4*)out);
  } else {
    gram_partial<8><<<BATCH * 8, 256, 0, stream>>>(R, I, ws);
    gram_reduce<8><<<256, 256, 0, stream>>>((const float4*)ws, (float4*)out);
  }
}